// Round 2
// baseline (854.074 us; speedup 1.0000x reference)
//
#include <hip/hip_runtime.h>

typedef unsigned short u16;
typedef unsigned int u32;
using short8 = __attribute__((ext_vector_type(8))) short;
using f32x4  = __attribute__((ext_vector_type(4))) float;
using u32x4  = __attribute__((ext_vector_type(4))) u32;
using u16x4  = __attribute__((ext_vector_type(4))) u16;

#define N_CNT 50000
#define E_CNT 800000

__device__ __forceinline__ u16 f2bf(float f) {
  u32 u = __builtin_bit_cast(u32, f);
  u += 0x7fffu + ((u >> 16) & 1u);
  return (u16)(u >> 16);
}
__device__ __forceinline__ float bf2f(u16 v) {
  u32 u = ((u32)v) << 16;
  return __builtin_bit_cast(float, u);
}
__device__ __forceinline__ float siluf(float v) {
  return __fdividef(v, 1.f + __expf(-v));
}

// ---------------- prep: h -> bf16 ----------------
__global__ void k_hb(const float* __restrict__ h, u16* __restrict__ hb) {
  int i = (blockIdx.x * 256 + threadIdx.x) * 4;   // 6250*256*4 == 6,400,000 exact
  f32x4 v = *reinterpret_cast<const f32x4*>(h + i);
  u16x4 o = { f2bf(v[0]), f2bf(v[1]), f2bf(v[2]), f2bf(v[3]) };
  *reinterpret_cast<u16x4*>(hb + i) = o;
}

// ---------------- prep: weight fragments (MFMA B layout) ----------------
// frag element (tile t, kstep s, lane l, i): B[k=32s+8*(l>>4)+i][n=16t+(l&15)]
__global__ void k_wf(const float* __restrict__ w1, const float* __restrict__ w2,
                     const float* __restrict__ wc1, const float* __restrict__ wn1,
                     const float* __restrict__ wn2,
                     u16* __restrict__ wef, u16* __restrict__ wnf) {
  int idx = blockIdx.x * 256 + threadIdx.x;     // 464*256 == 118784 exact
  if (idx < 36864) {                            // w1f: 8t x 9s, K=288 (>=273 zero-pad)
    int i = idx & 7, l = (idx >> 3) & 63, rest = idx >> 9;
    int s = rest % 9, t = rest / 9;
    int k = 32 * s + 8 * (l >> 4) + i, n = 16 * t + (l & 15);
    wef[idx] = (k < 273) ? f2bf(w1[k * 128 + n]) : (u16)0;
  } else if (idx < 53248) {                     // w2f: 8t x 4s
    int u = idx - 36864;
    int i = u & 7, l = (u >> 3) & 63, rest = u >> 9;
    int s = rest & 3, t = rest >> 2;
    int k = 32 * s + 8 * (l >> 4) + i, n = 16 * t + (l & 15);
    wef[idx] = f2bf(w2[k * 128 + n]);
  } else if (idx < 69632) {                     // wc1f: 8t x 4s
    int u = idx - 53248;
    int i = u & 7, l = (u >> 3) & 63, rest = u >> 9;
    int s = rest & 3, t = rest >> 2;
    int k = 32 * s + 8 * (l >> 4) + i, n = 16 * t + (l & 15);
    wef[idx] = f2bf(wc1[k * 128 + n]);
  } else if (idx < 102400) {                    // wn1f: 8t x 8s (K=256)
    int u = idx - 69632;
    int i = u & 7, l = (u >> 3) & 63, rest = u >> 9;
    int s = rest & 7, t = rest >> 3;
    int k = 32 * s + 8 * (l >> 4) + i, n = 16 * t + (l & 15);
    wnf[u] = f2bf(wn1[k * 128 + n]);
  } else if (idx < 118784) {                    // wn2f: 8t x 4s
    int u = idx - 102400;
    int i = u & 7, l = (u >> 3) & 63, rest = u >> 9;
    int s = rest & 3, t = rest >> 2;
    int k = 32 * s + 8 * (l >> 4) + i, n = 16 * t + (l & 15);
    wnf[32768 + u] = f2bf(wn2[k * 128 + n]);
  }
}

// ---------------- CSR build ----------------
__global__ void k_deg(const int* __restrict__ eidx, int* __restrict__ deg) {
  int e = blockIdx.x * 256 + threadIdx.x;       // 3125*256 == 800000 exact
  atomicAdd(&deg[eidx[e]], 1);
}

__global__ __launch_bounds__(1024)
void k_scan(const int* __restrict__ deg, int* __restrict__ rp) {
  __shared__ int wsum[16];
  __shared__ int carry_s;
  int tid = threadIdx.x, lane = tid & 63, wv = tid >> 6;
  if (tid == 0) carry_s = 0;
  __syncthreads();
  for (int base = 0; base < 50176; base += 1024) {
    int idx = base + tid;
    int v = (idx < N_CNT) ? deg[idx] : 0;
    int inc = v;
#pragma unroll
    for (int d = 1; d < 64; d <<= 1) {
      int u = __shfl_up(inc, d, 64);
      if (lane >= d) inc += u;
    }
    if (lane == 63) wsum[wv] = inc;
    __syncthreads();
    if (tid < 16) {
      int s = wsum[tid];
#pragma unroll
      for (int d = 1; d < 16; d <<= 1) {
        int u = __shfl_up(s, d, 16);
        if (tid >= d) s += u;
      }
      wsum[tid] = s;
    }
    __syncthreads();
    int carry = carry_s;
    int woff = (wv > 0) ? wsum[wv - 1] : 0;
    if (idx < N_CNT) rp[idx] = carry + woff + inc - v;  // exclusive
    __syncthreads();
    if (tid == 0) carry_s = carry + wsum[15];
    __syncthreads();
  }
  if (threadIdx.x == 0) rp[N_CNT] = E_CNT;
}

__global__ void k_scatter(const int* __restrict__ eidx, const int* __restrict__ rp,
                          int* __restrict__ cur, int* __restrict__ elist) {
  int e = blockIdx.x * 256 + threadIdx.x;
  int r = eidx[e];
  int p = atomicAdd(&cur[r], 1);
  elist[rp[r] + p] = e;
}

// ---------------- edge kernel ----------------
// LDS: w1f 73728 | w2f 32768 | wc1f 32768 | per-wave 5888
// MODE 0: atomic m_i (fallback).  MODE 1: stream m_ij rows to global.
template <int MODE>
__global__ __launch_bounds__(256, 1)
void egnn_edge(const u16* __restrict__ hb, const float* __restrict__ xc,
               const float* __restrict__ ea, const int* __restrict__ eidx,
               const u16* __restrict__ wef,
               const float* __restrict__ b1v, const float* __restrict__ b2v,
               const float* __restrict__ bc1v, const float* __restrict__ wc2v,
               float* __restrict__ m_i, u16* __restrict__ m_ij,
               float* __restrict__ x_acc) {
  extern __shared__ char smem[];
  const int tid = threadIdx.x;
  {
    const u32x4* src = reinterpret_cast<const u32x4*>(wef);
    u32x4* dst = reinterpret_cast<u32x4*>(smem);
    for (int i = tid; i < 8704; i += 256) dst[i] = src[i];
  }
  __syncthreads();
  const int w = tid >> 6, lane = tid & 63;
  const int g = lane >> 4, c15 = lane & 15;
  char* wb = smem + 139264 + w * 5888;
  u16* atail  = (u16*)wb;
  u16* mbuf   = (u16*)(wb + 1024);
  float* cd   = (float*)(wb + 5376);
  int* rcl    = (int*)(wb + 5632);
  float* dsqb = (float*)(wb + 5760);
  const u16* w1f  = (const u16*)smem;
  const u16* w2f  = (const u16*)(smem + 73728);
  const u16* wc1f = (const u16*)(smem + 106496);

  float b1r[8], b2r[8], bc1r[8], wc2r[8];
#pragma unroll
  for (int t = 0; t < 8; ++t) {
    b1r[t]  = b1v[t * 16 + c15];
    b2r[t]  = b2v[t * 16 + c15];
    bc1r[t] = bc1v[t * 16 + c15];
    wc2r[t] = wc2v[t * 16 + c15];
  }

  for (int tile = blockIdx.x; tile < E_CNT / 64; tile += gridDim.x) {
    const int ebase = tile * 64 + w * 16;
    if (lane < 16) {
      int gi = ebase + lane;
      int r = eidx[gi], c = eidx[E_CNT + gi];
      float d0 = xc[3 * r + 0] - xc[3 * c + 0];
      float d1 = xc[3 * r + 1] - xc[3 * c + 1];
      float d2 = xc[3 * r + 2] - xc[3 * c + 2];
      float dsq = d0 * d0 + d1 * d1 + d2 * d2;
      cd[lane * 4 + 0] = d0; cd[lane * 4 + 1] = d1; cd[lane * 4 + 2] = d2;
      cd[lane * 4 + 3] = rsqrtf(dsq + 1e-8f);
      dsqb[lane] = dsq;
      rcl[lane * 2 + 0] = r; rcl[lane * 2 + 1] = c;
    }
    {
      int e = lane >> 2, kk = (lane & 3) * 8;
      int gi = ebase + e;
      float dq = dsqb[e];
      short8 v;
#pragma unroll
      for (int j = 0; j < 8; ++j) {
        int kc = kk + j;
        float f = 0.f;
        if (kc == 0) f = dq;
        else if (kc <= 16) f = ea[gi * 16 + (kc - 1)];
        v[j] = (short)f2bf(f);
      }
      *reinterpret_cast<short8*>(atail + e * 32 + kk) = v;
    }
    int re = rcl[c15 * 2 + 0], ce = rcl[c15 * 2 + 1];
    short8 af[9];
#pragma unroll
    for (int s = 0; s < 4; ++s)
      af[s] = *reinterpret_cast<const short8*>(hb + re * 128 + s * 32 + g * 8);
#pragma unroll
    for (int s = 0; s < 4; ++s)
      af[4 + s] = *reinterpret_cast<const short8*>(hb + ce * 128 + s * 32 + g * 8);
    af[8] = *reinterpret_cast<const short8*>(atail + c15 * 32 + g * 8);

    f32x4 acc[8];
#pragma unroll
    for (int t = 0; t < 8; ++t) acc[t] = (f32x4){0.f, 0.f, 0.f, 0.f};
#pragma unroll
    for (int s = 0; s < 9; ++s) {
#pragma unroll
      for (int t = 0; t < 8; ++t) {
        short8 bf = *reinterpret_cast<const short8*>(w1f + ((t * 9 + s) * 64 + lane) * 8);
        acc[t] = __builtin_amdgcn_mfma_f32_16x16x32_bf16(af[s], bf, acc[t], 0, 0, 0);
      }
    }
#pragma unroll
    for (int t = 0; t < 8; ++t)
#pragma unroll
      for (int i = 0; i < 4; ++i) {
        float v = siluf(acc[t][i] + b1r[t]);
        mbuf[(g * 4 + i) * 136 + t * 16 + c15] = f2bf(v);
      }
    short8 a2[4];
#pragma unroll
    for (int s = 0; s < 4; ++s)
      a2[s] = *reinterpret_cast<const short8*>(mbuf + c15 * 136 + s * 32 + g * 8);
    f32x4 acc2[8];
#pragma unroll
    for (int t = 0; t < 8; ++t) acc2[t] = (f32x4){0.f, 0.f, 0.f, 0.f};
#pragma unroll
    for (int s = 0; s < 4; ++s) {
#pragma unroll
      for (int t = 0; t < 8; ++t) {
        short8 bf = *reinterpret_cast<const short8*>(w2f + ((t * 4 + s) * 64 + lane) * 8);
        acc2[t] = __builtin_amdgcn_mfma_f32_16x16x32_bf16(a2[s], bf, acc2[t], 0, 0, 0);
      }
    }
    if (MODE == 0) {
      int rows4[4];
#pragma unroll
      for (int i = 0; i < 4; ++i) rows4[i] = rcl[(g * 4 + i) * 2];
#pragma unroll
      for (int t = 0; t < 8; ++t)
#pragma unroll
        for (int i = 0; i < 4; ++i) {
          float v = siluf(acc2[t][i] + b2r[t]);
          atomicAdd(&m_i[rows4[i] * 128 + t * 16 + c15], v);
          mbuf[(g * 4 + i) * 136 + t * 16 + c15] = f2bf(v);
        }
    } else {
#pragma unroll
      for (int t = 0; t < 8; ++t)
#pragma unroll
        for (int i = 0; i < 4; ++i) {
          float v = siluf(acc2[t][i] + b2r[t]);
          mbuf[(g * 4 + i) * 136 + t * 16 + c15] = f2bf(v);
        }
      // stream m2 rows (= m_ij) to global, 16B/lane coalesced-ish
#pragma unroll
      for (int q = 0; q < 4; ++q) {
        short8 v = *reinterpret_cast<const short8*>(mbuf + c15 * 136 + q * 32 + g * 8);
        *reinterpret_cast<short8*>(m_ij + (size_t)(ebase + c15) * 128 + q * 32 + g * 8) = v;
      }
    }
    // coord MLP
    short8 a3[4];
#pragma unroll
    for (int s = 0; s < 4; ++s)
      a3[s] = *reinterpret_cast<const short8*>(mbuf + c15 * 136 + s * 32 + g * 8);
    f32x4 acc3[8];
#pragma unroll
    for (int t = 0; t < 8; ++t) acc3[t] = (f32x4){0.f, 0.f, 0.f, 0.f};
#pragma unroll
    for (int s = 0; s < 4; ++s) {
#pragma unroll
      for (int t = 0; t < 8; ++t) {
        short8 bf = *reinterpret_cast<const short8*>(wc1f + ((t * 4 + s) * 64 + lane) * 8);
        acc3[t] = __builtin_amdgcn_mfma_f32_16x16x32_bf16(a3[s], bf, acc3[t], 0, 0, 0);
      }
    }
    float p[4] = {0.f, 0.f, 0.f, 0.f};
#pragma unroll
    for (int t = 0; t < 8; ++t)
#pragma unroll
      for (int i = 0; i < 4; ++i)
        p[i] += siluf(acc3[t][i] + bc1r[t]) * wc2r[t];
#pragma unroll
    for (int m = 1; m <= 8; m <<= 1) {
#pragma unroll
      for (int i = 0; i < 4; ++i) p[i] += __shfl_xor(p[i], m, 64);
    }
    if (c15 == 0) {
#pragma unroll
      for (int i = 0; i < 4; ++i) {
        int e = g * 4 + i;
        float fac = cd[e * 4 + 3] * tanhf(p[i]);
        int r = rcl[e * 2];
        atomicAdd(&x_acc[r * 4 + 0], cd[e * 4 + 0] * fac);
        atomicAdd(&x_acc[r * 4 + 1], cd[e * 4 + 1] * fac);
        atomicAdd(&x_acc[r * 4 + 2], cd[e * 4 + 2] * fac);
        if (MODE == 0) atomicAdd(&x_acc[r * 4 + 3], 1.0f);
      }
    }
  }
}

// ---------------- node kernel (B-frags from global; static LDS) ----------------
// MODE 0: read m_i f32.  MODE 1: CSR-gather m_ij bf16 rows.
template <int MODE>
__global__ __launch_bounds__(256)
void egnn_node(const u16* __restrict__ hb, const float* __restrict__ h,
               const float* __restrict__ m_i, const u16* __restrict__ m_ij,
               const int* __restrict__ rp, const int* __restrict__ elist,
               const u16* __restrict__ wnf,
               const float* __restrict__ bn1, const float* __restrict__ bn2,
               const float* __restrict__ lng, const float* __restrict__ lnb,
               float* __restrict__ h_out) {
  __shared__ u16 mbuf_all[4][2176];
  const int tid = threadIdx.x, w = tid >> 6, lane = tid & 63;
  const int g = lane >> 4, c15 = lane & 15;
  u16* mbuf = mbuf_all[w];
  const u16* wn1f = wnf;
  const u16* wn2f = wnf + 32768;

  float bn1r[8], bn2r[8], lngr[8], lnbr[8];
#pragma unroll
  for (int t = 0; t < 8; ++t) {
    bn1r[t] = bn1[t * 16 + c15];
    bn2r[t] = bn2[t * 16 + c15];
    lngr[t] = lng[t * 16 + c15];
    lnbr[t] = lnb[t * 16 + c15];
  }

  for (int nt = blockIdx.x; nt < 782; nt += gridDim.x) {
    int nbase = nt * 64 + w * 16;
    if (nbase >= N_CNT) continue;   // 50000 = 781*64 + 16, wave-aligned tail
    int nr = nbase + c15;
    short8 af[8];
#pragma unroll
    for (int s = 0; s < 4; ++s)
      af[s] = *reinterpret_cast<const short8*>(hb + nr * 128 + s * 32 + g * 8);
    if (MODE == 0) {
#pragma unroll
      for (int s = 0; s < 4; ++s) {
        f32x4 v0 = *reinterpret_cast<const f32x4*>(m_i + nr * 128 + s * 32 + g * 8);
        f32x4 v1 = *reinterpret_cast<const f32x4*>(m_i + nr * 128 + s * 32 + g * 8 + 4);
        short8 t8;
#pragma unroll
        for (int j = 0; j < 4; ++j) t8[j] = (short)f2bf(v0[j]);
#pragma unroll
        for (int j = 0; j < 4; ++j) t8[4 + j] = (short)f2bf(v1[j]);
        af[4 + s] = t8;
      }
    } else {
      // CSR gather: lane (g,c15) accumulates cols [g*32, g*32+32) of node nr
      float macc[32];
#pragma unroll
      for (int k2 = 0; k2 < 32; ++k2) macc[k2] = 0.f;
      int beg = rp[nr], end = rp[nr + 1];
      for (int j = beg; j < end; ++j) {
        int e = elist[j];
        const u16* p = m_ij + (size_t)e * 128 + g * 32;
#pragma unroll
        for (int q = 0; q < 4; ++q) {
          short8 v = *reinterpret_cast<const short8*>(p + q * 8);
#pragma unroll
          for (int k2 = 0; k2 < 8; ++k2) macc[q * 8 + k2] += bf2f((u16)v[k2]);
        }
      }
      // redistribute via LDS to A-fragment layout
#pragma unroll
      for (int q = 0; q < 4; ++q) {
        short8 v;
#pragma unroll
        for (int k2 = 0; k2 < 8; ++k2) v[k2] = (short)f2bf(macc[q * 8 + k2]);
        *reinterpret_cast<short8*>(mbuf + c15 * 136 + g * 32 + q * 8) = v;
      }
#pragma unroll
      for (int s = 0; s < 4; ++s)
        af[4 + s] = *reinterpret_cast<const short8*>(mbuf + c15 * 136 + s * 32 + g * 8);
    }
    f32x4 acc[8];
#pragma unroll
    for (int t = 0; t < 8; ++t) acc[t] = (f32x4){0.f, 0.f, 0.f, 0.f};
#pragma unroll
    for (int s = 0; s < 8; ++s) {
#pragma unroll
      for (int t = 0; t < 8; ++t) {
        short8 bf = *reinterpret_cast<const short8*>(wn1f + ((t * 8 + s) * 64 + lane) * 8);
        acc[t] = __builtin_amdgcn_mfma_f32_16x16x32_bf16(af[s], bf, acc[t], 0, 0, 0);
      }
    }
#pragma unroll
    for (int t = 0; t < 8; ++t)
#pragma unroll
      for (int i = 0; i < 4; ++i) {
        float v = siluf(acc[t][i] + bn1r[t]);
        mbuf[(g * 4 + i) * 136 + t * 16 + c15] = f2bf(v);
      }
    short8 a2[4];
#pragma unroll
    for (int s = 0; s < 4; ++s)
      a2[s] = *reinterpret_cast<const short8*>(mbuf + c15 * 136 + s * 32 + g * 8);
    f32x4 acc2[8];
#pragma unroll
    for (int t = 0; t < 8; ++t) acc2[t] = (f32x4){0.f, 0.f, 0.f, 0.f};
#pragma unroll
    for (int s = 0; s < 4; ++s) {
#pragma unroll
      for (int t = 0; t < 8; ++t) {
        short8 bf = *reinterpret_cast<const short8*>(wn2f + ((t * 4 + s) * 64 + lane) * 8);
        acc2[t] = __builtin_amdgcn_mfma_f32_16x16x32_bf16(a2[s], bf, acc2[t], 0, 0, 0);
      }
    }
    float vres[8][4];
    float s1[4] = {0.f, 0.f, 0.f, 0.f}, s2[4] = {0.f, 0.f, 0.f, 0.f};
#pragma unroll
    for (int t = 0; t < 8; ++t)
#pragma unroll
      for (int i = 0; i < 4; ++i) {
        int n = nbase + g * 4 + i;
        float v = acc2[t][i] + bn2r[t] + h[n * 128 + t * 16 + c15];
        vres[t][i] = v; s1[i] += v; s2[i] += v * v;
      }
#pragma unroll
    for (int m = 1; m <= 8; m <<= 1) {
#pragma unroll
      for (int i = 0; i < 4; ++i) {
        s1[i] += __shfl_xor(s1[i], m, 64);
        s2[i] += __shfl_xor(s2[i], m, 64);
      }
    }
    float mu[4], rstd[4];
#pragma unroll
    for (int i = 0; i < 4; ++i) {
      mu[i] = s1[i] * (1.0f / 128.0f);
      float var = s2[i] * (1.0f / 128.0f) - mu[i] * mu[i];
      rstd[i] = rsqrtf(var + 1e-5f);
    }
#pragma unroll
    for (int t = 0; t < 8; ++t)
#pragma unroll
      for (int i = 0; i < 4; ++i) {
        int n = nbase + g * 4 + i;
        h_out[n * 128 + t * 16 + c15] =
            (vres[t][i] - mu[i]) * rstd[i] * lngr[t] + lnbr[t];
      }
  }
}

// ---------------- x_out ----------------
template <int MODE>
__global__ void egnn_xout(const float* __restrict__ x, const float* __restrict__ x_acc,
                          const int* __restrict__ deg, float* __restrict__ xo) {
  int n = blockIdx.x * 256 + threadIdx.x;
  if (n < N_CNT) {
    float dg = (MODE == 1) ? fmaxf((float)deg[n], 1.0f) : fmaxf(x_acc[n * 4 + 3], 1.0f);
    xo[n * 3 + 0] = x[n * 3 + 0] + x_acc[n * 4 + 0] / dg;
    xo[n * 3 + 1] = x[n * 3 + 1] + x_acc[n * 4 + 1] / dg;
    xo[n * 3 + 2] = x[n * 3 + 2] + x_acc[n * 4 + 2] / dg;
  }
}

extern "C" void kernel_launch(void* const* d_in, const int* in_sizes, int n_in,
                              void* d_out, int out_size, void* d_ws, size_t ws_size,
                              hipStream_t stream) {
  const float* h     = (const float*)d_in[0];
  const float* x     = (const float*)d_in[1];
  const float* ea    = (const float*)d_in[2];
  const float* we_w1 = (const float*)d_in[3];
  const float* we_b1 = (const float*)d_in[4];
  const float* we_w2 = (const float*)d_in[5];
  const float* we_b2 = (const float*)d_in[6];
  const float* wc_w1 = (const float*)d_in[7];
  const float* wc_b1 = (const float*)d_in[8];
  const float* wc_w2 = (const float*)d_in[9];
  const float* wn_w1 = (const float*)d_in[10];
  const float* wn_b1 = (const float*)d_in[11];
  const float* wn_w2 = (const float*)d_in[12];
  const float* wn_b2 = (const float*)d_in[13];
  const float* ln_g  = (const float*)d_in[14];
  const float* ln_b  = (const float*)d_in[15];
  const int* eidx    = (const int*)d_in[16];
  float* out = (float*)d_out;
  char* ws = (char*)d_ws;

  u16* hb  = (u16*)(ws);                         // 12,800,000
  u16* wef = (u16*)(ws + 12800000);              //    139,264
  u16* wnf = (u16*)(ws + 12939264);              //     98,304

  const bool big = ws_size >= 222437632ULL;

  k_hb<<<6250, 256, 0, stream>>>(h, hb);
  k_wf<<<464, 256, 0, stream>>>(we_w1, we_w2, wc_w1, wn_w1, wn_w2, wef, wnf);

  if (big) {
    float* xacc = (float*)(ws + 13037568);       //    800,000
    int* deg    = (int*)(ws + 13837568);         //    200,000
    int* rp     = (int*)(ws + 14037568);         //    200,016
    int* cur    = (int*)(ws + 14237584);         //    200,000
    int* elist  = (int*)(ws + 14437584);         //  3,200,000
    u16* m_ij   = (u16*)(ws + 17637632);         // 204,800,000

    hipMemsetAsync(ws + 13037568, 0, 1400016, stream);   // xacc+deg+rp+cur
    k_deg<<<3125, 256, 0, stream>>>(eidx, deg);
    k_scan<<<1, 1024, 0, stream>>>(deg, rp);
    k_scatter<<<3125, 256, 0, stream>>>(eidx, rp, cur, elist);

    hipFuncSetAttribute(reinterpret_cast<const void*>(egnn_edge<1>),
                        hipFuncAttributeMaxDynamicSharedMemorySize, 162816);
    egnn_edge<1><<<512, 256, 162816, stream>>>(hb, x, ea, eidx, wef,
                                               we_b1, we_b2, wc_b1, wc_w2,
                                               nullptr, m_ij, xacc);
    egnn_node<1><<<782, 256, 0, stream>>>(hb, h, nullptr, m_ij, rp, elist, wnf,
                                          wn_b1, wn_b2, ln_g, ln_b, out);
    egnn_xout<1><<<196, 256, 0, stream>>>(x, xacc, deg, out + 6400000);
  } else {
    float* xacc = (float*)(ws + 13037568);       //    800,000
    float* m_i  = (float*)(ws + 13837568);       // 25,600,000 (ends 39,437,568)
    hipMemsetAsync(ws + 13037568, 0, 26400000, stream);
    hipFuncSetAttribute(reinterpret_cast<const void*>(egnn_edge<0>),
                        hipFuncAttributeMaxDynamicSharedMemorySize, 162816);
    egnn_edge<0><<<512, 256, 162816, stream>>>(hb, x, ea, eidx, wef,
                                               we_b1, we_b2, wc_b1, wc_w2,
                                               m_i, nullptr, xacc);
    egnn_node<0><<<782, 256, 0, stream>>>(hb, h, m_i, nullptr, nullptr, nullptr, wnf,
                                          wn_b1, wn_b2, ln_g, ln_b, out);
    egnn_xout<0><<<196, 256, 0, stream>>>(x, xacc, nullptr, out + 6400000);
  }
}

// Round 3
// 503.817 us; speedup vs baseline: 1.6952x; 1.6952x over previous
//
#include <hip/hip_runtime.h>

typedef unsigned short u16;
typedef unsigned int u32;
using short8 = __attribute__((ext_vector_type(8))) short;
using f32x4  = __attribute__((ext_vector_type(4))) float;
using u32x4  = __attribute__((ext_vector_type(4))) u32;

#define N_CNT 50000
#define E_CNT 800000
#define EB_CNT 400000   // edges per batch (2 batches)

__device__ __forceinline__ u16 f2bf(float f) {
  u32 u = __builtin_bit_cast(u32, f);
  u += 0x7fffu + ((u >> 16) & 1u);
  return (u16)(u >> 16);
}
__device__ __forceinline__ float bf2f(u16 v) {
  u32 u = ((u32)v) << 16;
  return __builtin_bit_cast(float, u);
}
__device__ __forceinline__ float siluf(float v) {
  return __fdividef(v, 1.f + __expf(-v));
}

// ---------------- prep: weight fragments (MFMA B layout) ----------------
// frag element (tile t, kstep s, lane l, i): B[k=32s+8*(l>>4)+i][n=16t+(l&15)]
// wef:   w1tail [0,4096) | w2f [4096,20480) | wc1f [20480,36864)   (u16 idx)
// w1abf: 32768 u16   (K=128 -> N=256: [W1a | W1b], 16t x 4s)
// wnf:   wn1f 32768 | wn2f 16384
__global__ void k_wf(const float* __restrict__ w1, const float* __restrict__ w2,
                     const float* __restrict__ wc1, const float* __restrict__ wn1,
                     const float* __restrict__ wn2,
                     u16* __restrict__ wef, u16* __restrict__ w1abf,
                     u16* __restrict__ wnf) {
  int idx = blockIdx.x * 256 + threadIdx.x;     // 464*256 == 118784 exact
  int i = idx & 7, l = (idx >> 3) & 63;
  int kb = 8 * (l >> 4) + i;                    // k within 32-step
  int n16 = l & 15;
  if (idx < 4096) {                             // w1tail: 8t x 1s, k = 256..287 of W1
    int t = idx >> 9;
    int k = kb, n = 16 * t + n16;
    wef[idx] = (k < 17) ? f2bf(w1[(256 + k) * 128 + n]) : (u16)0;
  } else if (idx < 20480) {                     // w2f: 8t x 4s
    int u = idx - 4096, rest = u >> 9;
    int s = rest & 3, t = rest >> 2;
    wef[idx] = f2bf(w2[(32 * s + kb) * 128 + 16 * t + n16]);
  } else if (idx < 36864) {                     // wc1f: 8t x 4s
    int u = idx - 20480, rest = u >> 9;
    int s = rest & 3, t = rest >> 2;
    wef[idx] = f2bf(wc1[(32 * s + kb) * 128 + 16 * t + n16]);
  } else if (idx < 69632) {                     // w1abf: 16t x 4s, K=128, N=256
    int u = idx - 36864, rest = u >> 9;
    int s = rest & 3, t = rest >> 2;
    int k = 32 * s + kb, n = 16 * t + n16;
    float v = (n < 128) ? w1[k * 128 + n] : w1[(128 + k) * 128 + (n - 128)];
    w1abf[u] = f2bf(v);
  } else if (idx < 102400) {                    // wn1f: 8t x 8s (K=256)
    int u = idx - 69632, rest = u >> 9;
    int s = rest & 7, t = rest >> 3;
    wnf[u] = f2bf(wn1[(32 * s + kb) * 128 + 16 * t + n16]);
  } else if (idx < 118784) {                    // wn2f: 8t x 4s
    int u = idx - 102400, rest = u >> 9;
    int s = rest & 3, t = rest >> 2;
    wnf[32768 + u] = f2bf(wn2[(32 * s + kb) * 128 + 16 * t + n16]);
  }
}

// ---------------- hp = h @ [W1a|W1b] + [b1|0]  (bf16 [N][256]) ----------------
__global__ __launch_bounds__(256)
void k_hp(const float* __restrict__ h, const u16* __restrict__ w1abf,
          const float* __restrict__ b1v, u16* __restrict__ hp) {
  extern __shared__ char smem[];
  u16* wl = (u16*)smem;                          // 32768 u16 = 65536 B
  const int tid = threadIdx.x;
  {
    const u32x4* src = reinterpret_cast<const u32x4*>(w1abf);
    u32x4* dst = reinterpret_cast<u32x4*>(smem);
    for (int i2 = tid; i2 < 4096; i2 += 256) dst[i2] = src[i2];
  }
  __syncthreads();
  const int w = tid >> 6, lane = tid & 63;
  const int g = lane >> 4, c15 = lane & 15;
  float b1r[8];
#pragma unroll
  for (int t = 0; t < 8; ++t) b1r[t] = b1v[t * 16 + c15];

  int wt = blockIdx.x * 4 + w;                   // 782*4 = 3128 >= 3125
  if (wt >= 3125) return;
  int nbase = wt * 16;
  int nr = nbase + c15;
  short8 af[4];
#pragma unroll
  for (int s = 0; s < 4; ++s) {
    const float* p = h + nr * 128 + s * 32 + g * 8;
    f32x4 v0 = *reinterpret_cast<const f32x4*>(p);
    f32x4 v1 = *reinterpret_cast<const f32x4*>(p + 4);
    short8 t8;
#pragma unroll
    for (int j = 0; j < 4; ++j) t8[j] = (short)f2bf(v0[j]);
#pragma unroll
    for (int j = 0; j < 4; ++j) t8[4 + j] = (short)f2bf(v1[j]);
    af[s] = t8;
  }
  f32x4 acc[16];
#pragma unroll
  for (int t = 0; t < 16; ++t) acc[t] = (f32x4){0.f, 0.f, 0.f, 0.f};
#pragma unroll
  for (int s = 0; s < 4; ++s) {
#pragma unroll
    for (int t = 0; t < 16; ++t) {
      short8 bf = *reinterpret_cast<const short8*>(wl + ((t * 4 + s) * 64 + lane) * 8);
      acc[t] = __builtin_amdgcn_mfma_f32_16x16x32_bf16(af[s], bf, acc[t], 0, 0, 0);
    }
  }
#pragma unroll
  for (int t = 0; t < 16; ++t)
#pragma unroll
    for (int i = 0; i < 4; ++i) {
      int row = nbase + g * 4 + i;
      float v = acc[t][i] + ((t < 8) ? b1r[t] : 0.f);
      hp[row * 256 + t * 16 + c15] = f2bf(v);
    }
}

// ---------------- CSR build (per-batch) ----------------
__global__ void k_deg(const int* __restrict__ eidx, int* __restrict__ degs) {
  int e = blockIdx.x * 256 + threadIdx.x;       // 3125*256 == 800000
  int b = (e >= EB_CNT) ? 1 : 0;
  atomicAdd(&degs[b * N_CNT + eidx[e]], 1);
}

__global__ __launch_bounds__(1024)
void k_scan2(const int* __restrict__ degs, int* __restrict__ rps) {
  const int* deg = degs + blockIdx.x * N_CNT;
  int* rp = rps + blockIdx.x * (N_CNT + 1);
  __shared__ int wsum[16];
  __shared__ int carry_s;
  int tid = threadIdx.x, lane = tid & 63, wv = tid >> 6;
  if (tid == 0) carry_s = 0;
  __syncthreads();
  for (int base = 0; base < 50176; base += 1024) {
    int idx = base + tid;
    int v = (idx < N_CNT) ? deg[idx] : 0;
    int inc = v;
#pragma unroll
    for (int d = 1; d < 64; d <<= 1) {
      int u = __shfl_up(inc, d, 64);
      if (lane >= d) inc += u;
    }
    if (lane == 63) wsum[wv] = inc;
    __syncthreads();
    if (tid < 16) {
      int s = wsum[tid];
#pragma unroll
      for (int d = 1; d < 16; d <<= 1) {
        int u = __shfl_up(s, d, 16);
        if (tid >= d) s += u;
      }
      wsum[tid] = s;
    }
    __syncthreads();
    int carry = carry_s;
    int woff = (wv > 0) ? wsum[wv - 1] : 0;
    if (idx < N_CNT) rp[idx] = carry + woff + inc - v;
    __syncthreads();
    if (tid == 0) carry_s = carry + wsum[15];
    __syncthreads();
  }
  if (threadIdx.x == 0) rp[N_CNT] = EB_CNT;
}

__global__ void k_scatter(const int* __restrict__ eidx, const int* __restrict__ rps,
                          int* __restrict__ curs, int* __restrict__ pos) {
  int e = blockIdx.x * 256 + threadIdx.x;
  int b = (e >= EB_CNT) ? 1 : 0;
  int r = eidx[e];
  int p = atomicAdd(&curs[b * N_CNT + r], 1);
  pos[e] = rps[b * (N_CNT + 1) + r] + p;
}

// ---------------- edge kernel ----------------
// 1024 thr = 16 waves, 16 edges/wave. LDS: weights 73728 + 16*4352 = 143360.
// mbuf[16][136] u16 per wave; cols 128..135 = f32x4 {d0,d1,d2,dsq}.
__global__ __launch_bounds__(1024)
void egnn_edge2(const u16* __restrict__ hp, const float* __restrict__ xc,
                const float* __restrict__ ea, const int* __restrict__ eidx,
                const int* __restrict__ pos, const u16* __restrict__ wef,
                const float* __restrict__ b2v, const float* __restrict__ bc1v,
                const float* __restrict__ wc2v,
                u16* __restrict__ m_ij, float* __restrict__ x_acc, int ebase0) {
  extern __shared__ char smem[];
  const int tid = threadIdx.x;
  {
    const u32x4* src = reinterpret_cast<const u32x4*>(wef);
    u32x4* dst = reinterpret_cast<u32x4*>(smem);
    for (int i2 = tid; i2 < 4608; i2 += 1024) dst[i2] = src[i2];
  }
  __syncthreads();
  const int w = tid >> 6, lane = tid & 63;
  const int g = lane >> 4, c15 = lane & 15;
  const int e4 = lane >> 2, q4 = lane & 3;
  const u16* w1tf = (const u16*)smem;             //  8192 B
  const u16* w2f  = (const u16*)(smem + 8192);    // 32768 B
  const u16* wc1f = (const u16*)(smem + 40960);   // 32768 B
  u16* mbuf = (u16*)(smem + 73728 + w * 4352);

  float b2r[8], bc1r[8], wc2r[8];
#pragma unroll
  for (int t = 0; t < 8; ++t) {
    b2r[t]  = b2v[t * 16 + c15];
    bc1r[t] = bc1v[t * 16 + c15];
    wc2r[t] = wc2v[t * 16 + c15];
  }

  for (int bt = blockIdx.x; bt < 1563; bt += gridDim.x) {
    int wt = bt * 16 + w;
    if (wt >= 25000) continue;
    const int eb = ebase0 + wt * 16;
    // phase 1: geometry (lanes 0..15)
    int r_v = 0, c_v = 0, p_v = 0;
    if (lane < 16) {
      int gi = eb + lane;
      r_v = eidx[gi]; c_v = eidx[E_CNT + gi]; p_v = pos[gi];
      float d0 = xc[3 * r_v + 0] - xc[3 * c_v + 0];
      float d1 = xc[3 * r_v + 1] - xc[3 * c_v + 1];
      float d2 = xc[3 * r_v + 2] - xc[3 * c_v + 2];
      float dsq = d0 * d0 + d1 * d1 + d2 * d2;
      f32x4 cd = {d0, d1, d2, dsq};
      *reinterpret_cast<f32x4*>(mbuf + lane * 136 + 128) = cd;
    }
    int re4 = __shfl(r_v, e4, 64);
    int ce4 = __shfl(c_v, e4, 64);
    int pc15 = __shfl(p_v, c15, 64);
    // issue hp gathers early (hidden under tail MFMA)
    short8 ga[4], gb[4];
    {
      const u16* pa = hp + re4 * 256 + q4 * 32;
      const u16* pb = hp + ce4 * 256 + 128 + q4 * 32;
#pragma unroll
      for (int q = 0; q < 4; ++q) ga[q] = *reinterpret_cast<const short8*>(pa + q * 8);
#pragma unroll
      for (int q = 0; q < 4; ++q) gb[q] = *reinterpret_cast<const short8*>(pb + q * 8);
    }
    // tail A-tile cols 0..31 of mbuf rows: [dsq, ea0..15, 0..]
    {
      f32x4 eav = *reinterpret_cast<const f32x4*>(ea + (size_t)(eb + e4) * 16 + q4 * 4);
#pragma unroll
      for (int jj = 0; jj < 4; ++jj)
        mbuf[e4 * 136 + 1 + q4 * 4 + jj] = f2bf(eav[jj]);
      if (q4 == 0) {
        float dq = reinterpret_cast<const float*>(mbuf + e4 * 136 + 128)[3];
        mbuf[e4 * 136] = f2bf(dq);
      }
#pragma unroll
      for (int z = 17 + q4; z < 32; z += 4) mbuf[e4 * 136 + z] = 0;
    }
    // tail MFMA (K=32)
    short8 af8 = *reinterpret_cast<const short8*>(mbuf + c15 * 136 + g * 8);
    f32x4 acc[8];
#pragma unroll
    for (int t = 0; t < 8; ++t) acc[t] = (f32x4){0.f, 0.f, 0.f, 0.f};
#pragma unroll
    for (int t = 0; t < 8; ++t) {
      short8 bf = *reinterpret_cast<const short8*>(w1tf + (t * 64 + lane) * 8);
      acc[t] = __builtin_amdgcn_mfma_f32_16x16x32_bf16(af8, bf, acc[t], 0, 0, 0);
    }
    // raw C -> mbuf (no bias/silu yet)
#pragma unroll
    for (int t = 0; t < 8; ++t)
#pragma unroll
      for (int i = 0; i < 4; ++i)
        mbuf[(g * 4 + i) * 136 + t * 16 + c15] = f2bf(acc[t][i]);
    // combine: m1 = silu(hpa[row] + hpb[col] + tail)   (lane owns [e4][q4*32..+31])
#pragma unroll
    for (int q = 0; q < 4; ++q) {
      short8 tl = *reinterpret_cast<const short8*>(mbuf + e4 * 136 + q4 * 32 + q * 8);
      short8 o;
#pragma unroll
      for (int j = 0; j < 8; ++j) {
        float v = bf2f((u16)tl[j]) + bf2f((u16)ga[q][j]) + bf2f((u16)gb[q][j]);
        o[j] = (short)f2bf(siluf(v));
      }
      *reinterpret_cast<short8*>(mbuf + e4 * 136 + q4 * 32 + q * 8) = o;
    }
    // layer 2: m1 @ we_w2
    short8 a2[4];
#pragma unroll
    for (int s = 0; s < 4; ++s)
      a2[s] = *reinterpret_cast<const short8*>(mbuf + c15 * 136 + s * 32 + g * 8);
    f32x4 acc2[8];
#pragma unroll
    for (int t = 0; t < 8; ++t) acc2[t] = (f32x4){0.f, 0.f, 0.f, 0.f};
#pragma unroll
    for (int s = 0; s < 4; ++s) {
#pragma unroll
      for (int t = 0; t < 8; ++t) {
        short8 bf = *reinterpret_cast<const short8*>(w2f + ((t * 4 + s) * 64 + lane) * 8);
        acc2[t] = __builtin_amdgcn_mfma_f32_16x16x32_bf16(a2[s], bf, acc2[t], 0, 0, 0);
      }
    }
#pragma unroll
    for (int t = 0; t < 8; ++t)
#pragma unroll
      for (int i = 0; i < 4; ++i) {
        float v = siluf(acc2[t][i] + b2r[t]);
        mbuf[(g * 4 + i) * 136 + t * 16 + c15] = f2bf(v);
      }
    // stream m2 to m_ij[pos] + reuse as coord-MLP A fragments
    short8 a3[4];
#pragma unroll
    for (int q = 0; q < 4; ++q) {
      a3[q] = *reinterpret_cast<const short8*>(mbuf + c15 * 136 + q * 32 + g * 8);
      *reinterpret_cast<short8*>(m_ij + (size_t)pc15 * 128 + q * 32 + g * 8) = a3[q];
    }
    f32x4 acc3[8];
#pragma unroll
    for (int t = 0; t < 8; ++t) acc3[t] = (f32x4){0.f, 0.f, 0.f, 0.f};
#pragma unroll
    for (int s = 0; s < 4; ++s) {
#pragma unroll
      for (int t = 0; t < 8; ++t) {
        short8 bf = *reinterpret_cast<const short8*>(wc1f + ((t * 4 + s) * 64 + lane) * 8);
        acc3[t] = __builtin_amdgcn_mfma_f32_16x16x32_bf16(a3[s], bf, acc3[t], 0, 0, 0);
      }
    }
    float p4[4] = {0.f, 0.f, 0.f, 0.f};
#pragma unroll
    for (int t = 0; t < 8; ++t)
#pragma unroll
      for (int i = 0; i < 4; ++i)
        p4[i] += siluf(acc3[t][i] + bc1r[t]) * wc2r[t];
#pragma unroll
    for (int m = 1; m <= 8; m <<= 1) {
#pragma unroll
      for (int i = 0; i < 4; ++i) p4[i] += __shfl_xor(p4[i], m, 64);
    }
    int rr[4];
#pragma unroll
    for (int i = 0; i < 4; ++i) rr[i] = __shfl(r_v, g * 4 + i, 64);
    if (c15 == 0) {
#pragma unroll
      for (int i = 0; i < 4; ++i) {
        f32x4 cd = *reinterpret_cast<const f32x4*>(mbuf + (g * 4 + i) * 136 + 128);
        float fac = rsqrtf(cd[3] + 1e-8f) * tanhf(p4[i]);
        atomicAdd(&x_acc[rr[i] * 4 + 0], cd[0] * fac);
        atomicAdd(&x_acc[rr[i] * 4 + 1], cd[1] * fac);
        atomicAdd(&x_acc[rr[i] * 4 + 2], cd[2] * fac);
      }
    }
  }
}

// ---------------- gather: m_i[n] = sum of contiguous m_ij slot rows ----------------
template <int ACC>
__global__ __launch_bounds__(256)
void k_gather(const u16* __restrict__ m_ij, const int* __restrict__ rp,
              float* __restrict__ m_i) {
  const int tid = threadIdx.x, w = tid >> 6, lane = tid & 63;
  const int grp = lane >> 4, c16 = lane & 15;
  int node = blockIdx.x * 4 + w;                 // 12500*4 == 50000
  int beg = rp[node], end = rp[node + 1];
  float a[8] = {0.f, 0.f, 0.f, 0.f, 0.f, 0.f, 0.f, 0.f};
  for (int j = beg + grp; j < end; j += 4) {
    short8 v = *reinterpret_cast<const short8*>(m_ij + (size_t)j * 128 + c16 * 8);
#pragma unroll
    for (int k = 0; k < 8; ++k) a[k] += bf2f((u16)v[k]);
  }
#pragma unroll
  for (int k = 0; k < 8; ++k) {
    a[k] += __shfl_xor(a[k], 16, 64);
    a[k] += __shfl_xor(a[k], 32, 64);
  }
  if (grp == 0) {
    float* dst = m_i + node * 128 + c16 * 8;
    if (ACC) {
      f32x4 o0 = *reinterpret_cast<const f32x4*>(dst);
      f32x4 o1 = *reinterpret_cast<const f32x4*>(dst + 4);
#pragma unroll
      for (int k = 0; k < 4; ++k) { o0[k] += a[k]; o1[k] += a[4 + k]; }
      *reinterpret_cast<f32x4*>(dst) = o0;
      *reinterpret_cast<f32x4*>(dst + 4) = o1;
    } else {
      f32x4 o0 = {a[0], a[1], a[2], a[3]};
      f32x4 o1 = {a[4], a[5], a[6], a[7]};
      *reinterpret_cast<f32x4*>(dst) = o0;
      *reinterpret_cast<f32x4*>(dst + 4) = o1;
    }
  }
}

// ---------------- node kernel ----------------
__global__ __launch_bounds__(256)
void egnn_node2(const float* __restrict__ h, const float* __restrict__ m_i,
                const u16* __restrict__ wnf,
                const float* __restrict__ bn1, const float* __restrict__ bn2,
                const float* __restrict__ lng, const float* __restrict__ lnb,
                float* __restrict__ h_out) {
  __shared__ u16 mbuf_all[4][2176];
  const int tid = threadIdx.x, w = tid >> 6, lane = tid & 63;
  const int g = lane >> 4, c15 = lane & 15;
  u16* mbuf = mbuf_all[w];
  const u16* wn1f = wnf;
  const u16* wn2f = wnf + 32768;

  float bn1r[8], bn2r[8], lngr[8], lnbr[8];
#pragma unroll
  for (int t = 0; t < 8; ++t) {
    bn1r[t] = bn1[t * 16 + c15];
    bn2r[t] = bn2[t * 16 + c15];
    lngr[t] = lng[t * 16 + c15];
    lnbr[t] = lnb[t * 16 + c15];
  }

  int wt = blockIdx.x * 4 + w;                   // 782*4 = 3128 >= 3125
  if (wt >= 3125) return;
  int nbase = wt * 16;
  int nr = nbase + c15;
  short8 af[8];
#pragma unroll
  for (int s = 0; s < 4; ++s) {
    const float* p = h + nr * 128 + s * 32 + g * 8;
    f32x4 v0 = *reinterpret_cast<const f32x4*>(p);
    f32x4 v1 = *reinterpret_cast<const f32x4*>(p + 4);
    short8 t8;
#pragma unroll
    for (int j = 0; j < 4; ++j) t8[j] = (short)f2bf(v0[j]);
#pragma unroll
    for (int j = 0; j < 4; ++j) t8[4 + j] = (short)f2bf(v1[j]);
    af[s] = t8;
  }
#pragma unroll
  for (int s = 0; s < 4; ++s) {
    const float* p = m_i + nr * 128 + s * 32 + g * 8;
    f32x4 v0 = *reinterpret_cast<const f32x4*>(p);
    f32x4 v1 = *reinterpret_cast<const f32x4*>(p + 4);
    short8 t8;
#pragma unroll
    for (int j = 0; j < 4; ++j) t8[j] = (short)f2bf(v0[j]);
#pragma unroll
    for (int j = 0; j < 4; ++j) t8[4 + j] = (short)f2bf(v1[j]);
    af[4 + s] = t8;
  }
  f32x4 acc[8];
#pragma unroll
  for (int t = 0; t < 8; ++t) acc[t] = (f32x4){0.f, 0.f, 0.f, 0.f};
#pragma unroll
  for (int s = 0; s < 8; ++s) {
#pragma unroll
    for (int t = 0; t < 8; ++t) {
      short8 bf = *reinterpret_cast<const short8*>(wn1f + ((t * 8 + s) * 64 + lane) * 8);
      acc[t] = __builtin_amdgcn_mfma_f32_16x16x32_bf16(af[s], bf, acc[t], 0, 0, 0);
    }
  }
#pragma unroll
  for (int t = 0; t < 8; ++t)
#pragma unroll
    for (int i = 0; i < 4; ++i) {
      float v = siluf(acc[t][i] + bn1r[t]);
      mbuf[(g * 4 + i) * 136 + t * 16 + c15] = f2bf(v);
    }
  short8 a2[4];
#pragma unroll
  for (int s = 0; s < 4; ++s)
    a2[s] = *reinterpret_cast<const short8*>(mbuf + c15 * 136 + s * 32 + g * 8);
  f32x4 acc2[8];
#pragma unroll
  for (int t = 0; t < 8; ++t) acc2[t] = (f32x4){0.f, 0.f, 0.f, 0.f};
#pragma unroll
  for (int s = 0; s < 4; ++s) {
#pragma unroll
    for (int t = 0; t < 8; ++t) {
      short8 bf = *reinterpret_cast<const short8*>(wn2f + ((t * 4 + s) * 64 + lane) * 8);
      acc2[t] = __builtin_amdgcn_mfma_f32_16x16x32_bf16(a2[s], bf, acc2[t], 0, 0, 0);
    }
  }
  float vres[8][4];
  float s1[4] = {0.f, 0.f, 0.f, 0.f}, s2[4] = {0.f, 0.f, 0.f, 0.f};
#pragma unroll
  for (int t = 0; t < 8; ++t)
#pragma unroll
    for (int i = 0; i < 4; ++i) {
      int n = nbase + g * 4 + i;
      float v = acc2[t][i] + bn2r[t] + h[n * 128 + t * 16 + c15];
      vres[t][i] = v; s1[i] += v; s2[i] += v * v;
    }
#pragma unroll
  for (int m = 1; m <= 8; m <<= 1) {
#pragma unroll
    for (int i = 0; i < 4; ++i) {
      s1[i] += __shfl_xor(s1[i], m, 64);
      s2[i] += __shfl_xor(s2[i], m, 64);
    }
  }
  float mu[4], rstd[4];
#pragma unroll
  for (int i = 0; i < 4; ++i) {
    mu[i] = s1[i] * (1.0f / 128.0f);
    float var = s2[i] * (1.0f / 128.0f) - mu[i] * mu[i];
    rstd[i] = rsqrtf(var + 1e-5f);
  }
#pragma unroll
  for (int t = 0; t < 8; ++t)
#pragma unroll
    for (int i = 0; i < 4; ++i) {
      int n = nbase + g * 4 + i;
      h_out[n * 128 + t * 16 + c15] =
          (vres[t][i] - mu[i]) * rstd[i] * lngr[t] + lnbr[t];
    }
}

// ---------------- x_out ----------------
__global__ void egnn_xout(const float* __restrict__ x, const float* __restrict__ x_acc,
                          const int* __restrict__ degs, float* __restrict__ xo) {
  int n = blockIdx.x * 256 + threadIdx.x;
  if (n < N_CNT) {
    float dg = fmaxf((float)(degs[n] + degs[N_CNT + n]), 1.0f);
    xo[n * 3 + 0] = x[n * 3 + 0] + x_acc[n * 4 + 0] / dg;
    xo[n * 3 + 1] = x[n * 3 + 1] + x_acc[n * 4 + 1] / dg;
    xo[n * 3 + 2] = x[n * 3 + 2] + x_acc[n * 4 + 2] / dg;
  }
}

extern "C" void kernel_launch(void* const* d_in, const int* in_sizes, int n_in,
                              void* d_out, int out_size, void* d_ws, size_t ws_size,
                              hipStream_t stream) {
  const float* h     = (const float*)d_in[0];
  const float* x     = (const float*)d_in[1];
  const float* ea    = (const float*)d_in[2];
  const float* we_w1 = (const float*)d_in[3];
  const float* we_b1 = (const float*)d_in[4];
  const float* we_w2 = (const float*)d_in[5];
  const float* we_b2 = (const float*)d_in[6];
  const float* wc_w1 = (const float*)d_in[7];
  const float* wc_b1 = (const float*)d_in[8];
  const float* wc_w2 = (const float*)d_in[9];
  const float* wn_w1 = (const float*)d_in[10];
  const float* wn_b1 = (const float*)d_in[11];
  const float* wn_w2 = (const float*)d_in[12];
  const float* wn_b2 = (const float*)d_in[13];
  const float* ln_g  = (const float*)d_in[14];
  const float* ln_b  = (const float*)d_in[15];
  const int* eidx    = (const int*)d_in[16];
  float* out = (float*)d_out;
  char* ws = (char*)d_ws;

  // layout (bytes, all 16-aligned):
  u16* wef    = (u16*)(ws);                      //     73,728
  u16* w1abf  = (u16*)(ws + 73728);              //     65,536
  u16* wnf    = (u16*)(ws + 139264);             //     98,304
  u16* hp     = (u16*)(ws + 237568);             // 25,600,000
  float* m_i  = (float*)(ws + 25837568);         // 25,600,000
  float* xacc = (float*)(ws + 51437568);         //    800,000
  int* degs   = (int*)(ws + 52237568);           //    400,000 (2 x 50000)
  int* curs   = (int*)(ws + 52637568);           //    400,000
  int* rps    = (int*)(ws + 53037568);           //    400,008 (2 x 50001) -> pad 400,016
  int* pos    = (int*)(ws + 53437584);           //  3,200,000
  u16* m_ij   = (u16*)(ws + 56637584);           // 102,400,000  (end 159,037,584)

  k_wf<<<464, 256, 0, stream>>>(we_w1, we_w2, wc_w1, wn_w1, wn_w2, wef, w1abf, wnf);

  hipFuncSetAttribute(reinterpret_cast<const void*>(k_hp),
                      hipFuncAttributeMaxDynamicSharedMemorySize, 65536);
  k_hp<<<782, 256, 65536, stream>>>(h, w1abf, we_b1, hp);

  hipMemsetAsync(ws + 51437568, 0, 1600000, stream);   // xacc + degs + curs
  k_deg<<<3125, 256, 0, stream>>>(eidx, degs);
  k_scan2<<<2, 1024, 0, stream>>>(degs, rps);
  k_scatter<<<3125, 256, 0, stream>>>(eidx, rps, curs, pos);

  hipFuncSetAttribute(reinterpret_cast<const void*>(egnn_edge2),
                      hipFuncAttributeMaxDynamicSharedMemorySize, 143360);
  egnn_edge2<<<256, 1024, 143360, stream>>>(hp, x, ea, eidx, pos, wef,
                                            we_b2, wc_b1, wc_w2, m_ij, xacc, 0);
  k_gather<0><<<12500, 256, 0, stream>>>(m_ij, rps, m_i);
  egnn_edge2<<<256, 1024, 143360, stream>>>(hp, x, ea, eidx, pos, wef,
                                            we_b2, wc_b1, wc_w2, m_ij, xacc, EB_CNT);
  k_gather<1><<<12500, 256, 0, stream>>>(m_ij, rps + (N_CNT + 1), m_i);

  egnn_node2<<<782, 256, 0, stream>>>(h, m_i, wnf, wn_b1, wn_b2, ln_g, ln_b, out);
  egnn_xout<<<196, 256, 0, stream>>>(x, xacc, degs, out + 6400000);
}